// Round 4
// baseline (409.178 us; speedup 1.0000x reference)
//
#include <hip/hip_runtime.h>
#include <math.h>
#include <float.h>
#include <limits.h>

#define BN      32768   // B*N query rows
#define D_IN    1024
#define E_DIM   128
#define CB_N    8192

typedef _Float16 f16x8 __attribute__((ext_vector_type(8)));
typedef _Float16 f16x4 __attribute__((ext_vector_type(4)));
typedef float    f32x4 __attribute__((ext_vector_type(4)));

// async global->LDS, 16 B per lane. LDS dest = wave-uniform base + lane*16.
#define GLL16(gsrc, ldst)                                                      \
    __builtin_amdgcn_global_load_lds(                                          \
        (const __attribute__((address_space(1))) unsigned int*)(const void*)(gsrc), \
        (__attribute__((address_space(3))) unsigned int*)(void*)(ldst), 16, 0, 0)

// Workspace:
//   ph  : [CB_N/16][4][64][8] f16   2 MB  (ncb*256 hi, B-frag packed)
//   pl  : same                      2 MB
//   rph : [32*8][64][8] f16         0.25 MB (rp*64 hi, B-frag packed)
//   rpl : same                      0.25 MB

// ---------------------------------------------------------------------------
// Kernel 1 (fused packs): blocks [0,512) pack codebook, blocks [512,544)
// pack rp via LDS-staged coalesced loads. (validated r1/r2/r3)
// ---------------------------------------------------------------------------
__global__ __launch_bounds__(256) void pack_all_kernel(
    const float* __restrict__ cb, _Float16* __restrict__ ph,
    _Float16* __restrict__ pl,
    const float* __restrict__ rp, _Float16* __restrict__ rph,
    _Float16* __restrict__ rpl) {
    __shared__ float L[16][129];
    __shared__ float R[32][132];
    const int t = threadIdx.x;
    const int b = blockIdx.x;

    if (b < 512) {
        const int g = b;
        const int c = t >> 4, p = t & 15;
        const float4 v0 = *(const float4*)&cb[(size_t)(g * 16 + c) * E_DIM + p * 8];
        const float4 v1 = *(const float4*)&cb[(size_t)(g * 16 + c) * E_DIM + p * 8 + 4];
        float ss = v0.x * v0.x + v0.y * v0.y + v0.z * v0.z + v0.w * v0.w
                 + v1.x * v1.x + v1.y * v1.y + v1.z * v1.z + v1.w * v1.w;
#pragma unroll
        for (int m = 1; m < 16; m <<= 1) ss += __shfl_xor(ss, m);
        const float inv = 256.0f / fmaxf(sqrtf(ss), 1e-12f);

        L[c][p * 8 + 0] = v0.x * inv; L[c][p * 8 + 1] = v0.y * inv;
        L[c][p * 8 + 2] = v0.z * inv; L[c][p * 8 + 3] = v0.w * inv;
        L[c][p * 8 + 4] = v1.x * inv; L[c][p * 8 + 5] = v1.y * inv;
        L[c][p * 8 + 6] = v1.z * inv; L[c][p * 8 + 7] = v1.w * inv;
        __syncthreads();

        const int kb = t >> 6, lane = t & 63;
        const int quad = (lane >> 4), col = lane & 15;
        f16x8 h, l;
#pragma unroll
        for (int j = 0; j < 8; ++j) {
            const float v = L[col][kb * 32 + quad * 8 + j];
            const _Float16 hv = (_Float16)v;
            h[j] = hv;
            l[j] = (_Float16)(v - (float)hv);
        }
        const size_t off = ((size_t)(g * 4 + kb) * 64 + lane) * 8;
        *(f16x8*)&ph[off] = h;
        *(f16x8*)&pl[off] = l;
    } else {
        const int kb = b - 512;
        const int r = t >> 3, c0 = (t & 7) * 16;
#pragma unroll
        for (int i = 0; i < 4; ++i)
            *(float4*)&R[r][c0 + i * 4] =
                *(const float4*)&rp[(size_t)(kb * 32 + r) * E_DIM + c0 + i * 4];
        __syncthreads();

        const int w = t >> 6, lane = t & 63;
        const int quad = lane >> 4, col = lane & 15;
#pragma unroll
        for (int h2 = 0; h2 < 2; ++h2) {
            const int nt = w * 2 + h2;
            f16x8 hh, ll;
#pragma unroll
            for (int j = 0; j < 8; ++j) {
                const float v = R[quad * 8 + j][nt * 16 + col] * 64.0f;
                const _Float16 hv = (_Float16)v;
                hh[j] = hv;
                ll[j] = (_Float16)(v - (float)hv);
            }
            const size_t off = ((size_t)((kb * 8 + nt) * 64) + lane) * 8;
            *(f16x8*)&rph[off] = hh;
            *(f16x8*)&rpl[off] = ll;
        }
    }
}

// ---------------------------------------------------------------------------
// Kernel 2: FUSED proj + scores + argmax. Qtile=128, 512 threads, 8 waves,
// grid 256 (1 block/CU).
// Phase 1 (r1/r3-validated): barrier-free direct-from-global proj; wave w:
//   wq1=w>>2 (query 64-half), wn=w&3 (e-tile pair). P[128][132] f32 -> LDS.
// Phase 2 (r4): wave w: wq=w>>1 owns m-tiles {wq*2,wq*2+1} (32 queries),
//   wc=w&1 scans code half. Each 1KB B-frag LDS read feeds 2 MFMAs (B reuse
//   across M) -> per-CU LDS reads 32MB -> 16MB; MFMA is the binding pipe.
//   Staging unchanged from r3: global_load_lds DMA, 64-code double-buffered
//   chunks (32 codes per half per chunk) aliasing the dead P buffer.
// ---------------------------------------------------------------------------
#define PPITCH   132                  // proj buffer row pitch (dwords)
#define P_BYTES  (128 * PPITCH * 4)   // 67,584 B
#define CH_BYTES 32768                // 2 halves x 2 tiles x (hi+lo) x 4KB
#define NCHUNK   128                  // 4096 codes per half / 32

__global__ __launch_bounds__(512, 2) void fused_kernel(
    const float* __restrict__ x,
    const _Float16* __restrict__ rph, const _Float16* __restrict__ rpl,
    const _Float16* __restrict__ ph, const _Float16* __restrict__ pl,
    int* __restrict__ out) {
    __shared__ __align__(16) char SMEM[P_BYTES];   // P (phase1) | Bst[2] (phase2)
    __shared__ float ls[8][32];
    __shared__ int   li[8][32];

    const int tid  = threadIdx.x;
    const int lane = tid & 63;
    const int w    = tid >> 6;
    const int quad = lane >> 4, col = lane & 15;
    const int qb   = blockIdx.x * 128;

    float* Pf  = (float*)SMEM;
    char*  Bst = SMEM;

    // ======================= Phase 1: projection (LDS-free) =================
    const int wn  = w & 3;      // e-tile pair: nt = wn*2 + h
    const int wq1 = w >> 2;     // query 64-half
    const int qbw = qb + wq1 * 64;

    const float* xr[4];
#pragma unroll
    for (int mt = 0; mt < 4; ++mt)
        xr[mt] = x + (size_t)(qbw + mt * 16 + col) * D_IN + quad * 8;

    f32x4 acc[4][2];
#pragma unroll
    for (int mt = 0; mt < 4; ++mt)
#pragma unroll
        for (int h = 0; h < 2; ++h) acc[mt][h] = (f32x4){0.f, 0.f, 0.f, 0.f};

    float4 pA[4][2];
#pragma unroll
    for (int mt = 0; mt < 4; ++mt) {
        pA[mt][0] = *(const float4*)(xr[mt] + 0);
        pA[mt][1] = *(const float4*)(xr[mt] + 4);
    }
    f16x8 bhc[2], blc[2];
#pragma unroll
    for (int h = 0; h < 2; ++h) {
        const size_t off = ((size_t)(wn * 2 + h) * 64 + lane) * 8;
        bhc[h] = *(const f16x8*)&rph[off];
        blc[h] = *(const f16x8*)&rpl[off];
    }

    for (int kb = 0; kb < 32; ++kb) {
        f16x8 ah1[4], al1[4];
#pragma unroll
        for (int mt = 0; mt < 4; ++mt) {
            const float vv[8] = {pA[mt][0].x, pA[mt][0].y, pA[mt][0].z, pA[mt][0].w,
                                 pA[mt][1].x, pA[mt][1].y, pA[mt][1].z, pA[mt][1].w};
            f16x8 hh, ll;
#pragma unroll
            for (int j = 0; j < 8; ++j) {
                const float v = vv[j] * 512.0f;
                const _Float16 hv = (_Float16)v;
                hh[j] = hv;
                ll[j] = (_Float16)(v - (float)hv);
            }
            ah1[mt] = hh;
            al1[mt] = ll;
        }

        if (kb + 1 < 32) {
#pragma unroll
            for (int mt = 0; mt < 4; ++mt) {
                pA[mt][0] = *(const float4*)(xr[mt] + (kb + 1) * 32);
                pA[mt][1] = *(const float4*)(xr[mt] + (kb + 1) * 32 + 4);
            }
        }

        f16x8 bh1[2] = {bhc[0], bhc[1]};
        f16x8 bl1[2] = {blc[0], blc[1]};
        if (kb + 1 < 32) {
#pragma unroll
            for (int h = 0; h < 2; ++h) {
                const size_t off = ((size_t)((kb + 1) * 8 + wn * 2 + h) * 64 + lane) * 8;
                bhc[h] = *(const f16x8*)&rph[off];
                blc[h] = *(const f16x8*)&rpl[off];
            }
        }

#pragma unroll
        for (int mt = 0; mt < 4; ++mt)
#pragma unroll
            for (int h = 0; h < 2; ++h)
                acc[mt][h] = __builtin_amdgcn_mfma_f32_16x16x32_f16(ah1[mt], bh1[h], acc[mt][h], 0, 0, 0);
#pragma unroll
        for (int mt = 0; mt < 4; ++mt)
#pragma unroll
            for (int h = 0; h < 2; ++h)
                acc[mt][h] = __builtin_amdgcn_mfma_f32_16x16x32_f16(ah1[mt], bl1[h], acc[mt][h], 0, 0, 0);
#pragma unroll
        for (int mt = 0; mt < 4; ++mt)
#pragma unroll
            for (int h = 0; h < 2; ++h)
                acc[mt][h] = __builtin_amdgcn_mfma_f32_16x16x32_f16(al1[mt], bh1[h], acc[mt][h], 0, 0, 0);
    }

    // Write proj*16 (f32) to LDS. C/D: row = mt*16 + quad*4 + r, col(e) = h*16 + col.
#pragma unroll
    for (int mt = 0; mt < 4; ++mt)
#pragma unroll
        for (int h = 0; h < 2; ++h)
#pragma unroll
            for (int r = 0; r < 4; ++r) {
                const int row = wq1 * 64 + mt * 16 + quad * 4 + r;
                const int cc  = wn * 32 + h * 16 + col;
                Pf[row * PPITCH + cc] = acc[mt][h][r] * (1.0f / 2048.0f);
            }
    __syncthreads();

    // ======================= Phase 2: scores + argmax =======================
    const int wq = w >> 1;   // query quarter: m-tiles wq*2, wq*2+1
    const int wc = w & 1;    // code half: [wc*4096, wc*4096+4096)

    // A frags from P: A[m=col][k=quad*8+j], split hi/lo, 2 m-tiles.
    f16x8 ah[2][4], al[2][4];
#pragma unroll
    for (int mt2 = 0; mt2 < 2; ++mt2)
#pragma unroll
        for (int kb = 0; kb < 4; ++kb) {
            const int base = ((wq * 2 + mt2) * 16 + col) * PPITCH + kb * 32 + quad * 8;
            const float4 v0 = *(const float4*)&Pf[base];
            const float4 v1 = *(const float4*)&Pf[base + 4];
            const float vv[8] = {v0.x, v0.y, v0.z, v0.w, v1.x, v1.y, v1.z, v1.w};
            f16x8 hh, ll;
#pragma unroll
            for (int j = 0; j < 8; ++j) {
                const _Float16 hv = (_Float16)vv[j];
                hh[j] = hv;
                ll[j] = (_Float16)(vv[j] - (float)hv);
            }
            ah[mt2][kb] = hh;
            al[mt2][kb] = ll;
        }
    __syncthreads();   // everyone done with P; Bst may now overwrite it

    // Staging: 32 x 1KB DMA per chunk, 4 per wave. idx = h2*16 + tt*8 + sel*4 + kb.
    // LDS: off = buf*CH_BYTES + idx*1024 (+ lane*16 by HW).
    // Global 16-code tile G = h2*256 + c*2 + tt; src = (sel? pl : ph) + (G*4+kb)*1024.
    const char* const sb[2] = {(const char*)ph, (const char*)pl};
    int sh2[4], stt[4], ssel[4], skb[4];
#pragma unroll
    for (int i = 0; i < 4; ++i) {
        const int idx = w * 4 + i;
        sh2[i] = idx >> 4; stt[i] = (idx >> 3) & 1; ssel[i] = (idx >> 2) & 1; skb[i] = idx & 3;
    }

    // prologue: stage chunk 0 into buf 0
#pragma unroll
    for (int i = 0; i < 4; ++i) {
        const int G = sh2[i] * 256 + 0 * 2 + stt[i];
        const char* g = sb[ssel[i]] + (size_t)(G * 4 + skb[i]) * 1024 + (size_t)lane * 16;
        char* l = Bst + (w * 4 + i) * 1024;
        GLL16(g, l);
    }
    __syncthreads();

    float bs[8];
    int   bi[8];
#pragma unroll
    for (int s = 0; s < 8; ++s) { bs[s] = -FLT_MAX; bi[s] = 0; }

    for (int c = 0; c < NCHUNK; ++c) {
        const int cur = c & 1;
        // issue next-chunk DMA early (lands during this chunk's 48 MFMAs)
        if (c + 1 < NCHUNK) {
            const int nxt = cur ^ 1;
#pragma unroll
            for (int i = 0; i < 4; ++i) {
                const int G = sh2[i] * 256 + (c + 1) * 2 + stt[i];
                const char* g = sb[ssel[i]] + (size_t)(G * 4 + skb[i]) * 1024 + (size_t)lane * 16;
                char* l = Bst + nxt * CH_BYTES + (w * 4 + i) * 1024;
                GLL16(g, l);
            }
        }

        // this wave's half within the chunk: 2 tiles of 16 codes
        const char* bb = Bst + cur * CH_BYTES + wc * 16384 + (size_t)lane * 16;
#pragma unroll
        for (int tt = 0; tt < 2; ++tt) {
            f16x8 bh2[4], bl2[4];
#pragma unroll
            for (int kb = 0; kb < 4; ++kb) {
                bh2[kb] = *(const f16x8*)(bb + tt * 8192 + kb * 1024);
                bl2[kb] = *(const f16x8*)(bb + tt * 8192 + 4096 + kb * 1024);
            }

            f32x4 s0 = (f32x4){0.f, 0.f, 0.f, 0.f};
            f32x4 s1 = (f32x4){0.f, 0.f, 0.f, 0.f};

            __builtin_amdgcn_s_setprio(1);
#pragma unroll
            for (int kb = 0; kb < 4; ++kb) {
                s0 = __builtin_amdgcn_mfma_f32_16x16x32_f16(ah[0][kb], bh2[kb], s0, 0, 0, 0);
                s1 = __builtin_amdgcn_mfma_f32_16x16x32_f16(ah[1][kb], bh2[kb], s1, 0, 0, 0);
            }
#pragma unroll
            for (int kb = 0; kb < 4; ++kb) {
                s0 = __builtin_amdgcn_mfma_f32_16x16x32_f16(ah[0][kb], bl2[kb], s0, 0, 0, 0);
                s1 = __builtin_amdgcn_mfma_f32_16x16x32_f16(ah[1][kb], bl2[kb], s1, 0, 0, 0);
            }
#pragma unroll
            for (int kb = 0; kb < 4; ++kb) {
                s0 = __builtin_amdgcn_mfma_f32_16x16x32_f16(al[0][kb], bh2[kb], s0, 0, 0, 0);
                s1 = __builtin_amdgcn_mfma_f32_16x16x32_f16(al[1][kb], bh2[kb], s1, 0, 0, 0);
            }
            __builtin_amdgcn_s_setprio(0);

            const int code = wc * 4096 + c * 32 + tt * 16 + col;
#pragma unroll
            for (int r = 0; r < 4; ++r) {
                if (s0[r] > bs[r]) { bs[r] = s0[r]; bi[r] = code; }      // ascending: > keeps min idx
            }
#pragma unroll
            for (int r = 0; r < 4; ++r) {
                if (s1[r] > bs[4 + r]) { bs[4 + r] = s1[r]; bi[4 + r] = code; }
            }
        }

        if (c + 1 < NCHUNK) __syncthreads();
    }

    // Reduce the 16 code-columns per query (lanes differ in low 4 bits).
#pragma unroll
    for (int s = 0; s < 8; ++s) {
#pragma unroll
        for (int m = 1; m < 16; m <<= 1) {
            const float os = __shfl_xor(bs[s], m);
            const int   oi = __shfl_xor(bi[s], m);
            if (os > bs[s] || (os == bs[s] && oi < bi[s])) { bs[s] = os; bi[s] = oi; }
        }
    }

    if (col == 0) {
#pragma unroll
        for (int mt2 = 0; mt2 < 2; ++mt2)
#pragma unroll
            for (int r = 0; r < 4; ++r) {
                ls[w][mt2 * 16 + quad * 4 + r] = bs[mt2 * 4 + r];
                li[w][mt2 * 16 + quad * 4 + r] = bi[mt2 * 4 + r];
            }
    }
    __syncthreads();

    // Merge the two code halves (wc=0 codes < wc=1 codes: strict > keeps min idx).
    if (tid < 128) {
        const int q   = tid;
        const int wqf = q >> 5;
        const int q32 = q & 31;
        float s = ls[wqf * 2 + 0][q32];
        int   i = li[wqf * 2 + 0][q32];
        const float os = ls[wqf * 2 + 1][q32];
        if (os > s) { s = os; i = li[wqf * 2 + 1][q32]; }
        out[qb + q] = i;
    }
}

// ---------------------------------------------------------------------------
extern "C" void kernel_launch(void* const* d_in, const int* in_sizes, int n_in,
                              void* d_out, int out_size, void* d_ws, size_t ws_size,
                              hipStream_t stream) {
    const float* x  = (const float*)d_in[0];   // [8,4096,1024]
    const float* rp = (const float*)d_in[1];   // [1024,128]
    const float* cb = (const float*)d_in[2];   // [8192,128]
    int* out = (int*)d_out;                    // [8,4096] int32

    _Float16* ph  = (_Float16*)d_ws;                         // 2 MB
    _Float16* pl  = ph  + (size_t)CB_N * E_DIM;              // 2 MB
    _Float16* rph = pl  + (size_t)CB_N * E_DIM;              // 256 KB
    _Float16* rpl = rph + (size_t)D_IN * E_DIM;              // 256 KB

    pack_all_kernel<<<CB_N / 16 + 32, 256, 0, stream>>>(cb, ph, pl, rp, rph, rpl);
    fused_kernel<<<BN / 128, 512, 0, stream>>>(x, rph, rpl, ph, pl, out);
}

// Round 5
// 390.385 us; speedup vs baseline: 1.0481x; 1.0481x over previous
//
#include <hip/hip_runtime.h>
#include <math.h>
#include <float.h>
#include <limits.h>

#define BN      32768   // B*N query rows
#define D_IN    1024
#define E_DIM   128
#define CB_N    8192

typedef _Float16 f16x8 __attribute__((ext_vector_type(8)));
typedef _Float16 f16x4 __attribute__((ext_vector_type(4)));
typedef float    f32x4 __attribute__((ext_vector_type(4)));

// async global->LDS, 16 B per lane. LDS dest = wave-uniform base + lane*16.
#define GLL16(gsrc, ldst)                                                      \
    __builtin_amdgcn_global_load_lds(                                          \
        (const __attribute__((address_space(1))) unsigned int*)(const void*)(gsrc), \
        (__attribute__((address_space(3))) unsigned int*)(void*)(ldst), 16, 0, 0)

// Workspace:
//   ph  : [CB_N/16][4][64][8] f16   2 MB  (ncb*256 hi, B-frag packed)
//   pl  : same                      2 MB
//   rph : [32*8][64][8] f16         0.25 MB (rp*64 hi, B-frag packed)
//   rpl : same                      0.25 MB

// ---------------------------------------------------------------------------
// Kernel 1 (fused packs): blocks [0,512) pack codebook, blocks [512,544)
// pack rp via LDS-staged coalesced loads. (validated r1-r4)
// ---------------------------------------------------------------------------
__global__ __launch_bounds__(256) void pack_all_kernel(
    const float* __restrict__ cb, _Float16* __restrict__ ph,
    _Float16* __restrict__ pl,
    const float* __restrict__ rp, _Float16* __restrict__ rph,
    _Float16* __restrict__ rpl) {
    __shared__ float L[16][129];
    __shared__ float R[32][132];
    const int t = threadIdx.x;
    const int b = blockIdx.x;

    if (b < 512) {
        const int g = b;
        const int c = t >> 4, p = t & 15;
        const float4 v0 = *(const float4*)&cb[(size_t)(g * 16 + c) * E_DIM + p * 8];
        const float4 v1 = *(const float4*)&cb[(size_t)(g * 16 + c) * E_DIM + p * 8 + 4];
        float ss = v0.x * v0.x + v0.y * v0.y + v0.z * v0.z + v0.w * v0.w
                 + v1.x * v1.x + v1.y * v1.y + v1.z * v1.z + v1.w * v1.w;
#pragma unroll
        for (int m = 1; m < 16; m <<= 1) ss += __shfl_xor(ss, m);
        const float inv = 256.0f / fmaxf(sqrtf(ss), 1e-12f);

        L[c][p * 8 + 0] = v0.x * inv; L[c][p * 8 + 1] = v0.y * inv;
        L[c][p * 8 + 2] = v0.z * inv; L[c][p * 8 + 3] = v0.w * inv;
        L[c][p * 8 + 4] = v1.x * inv; L[c][p * 8 + 5] = v1.y * inv;
        L[c][p * 8 + 6] = v1.z * inv; L[c][p * 8 + 7] = v1.w * inv;
        __syncthreads();

        const int kb = t >> 6, lane = t & 63;
        const int quad = (lane >> 4), col = lane & 15;
        f16x8 h, l;
#pragma unroll
        for (int j = 0; j < 8; ++j) {
            const float v = L[col][kb * 32 + quad * 8 + j];
            const _Float16 hv = (_Float16)v;
            h[j] = hv;
            l[j] = (_Float16)(v - (float)hv);
        }
        const size_t off = ((size_t)(g * 4 + kb) * 64 + lane) * 8;
        *(f16x8*)&ph[off] = h;
        *(f16x8*)&pl[off] = l;
    } else {
        const int kb = b - 512;
        const int r = t >> 3, c0 = (t & 7) * 16;
#pragma unroll
        for (int i = 0; i < 4; ++i)
            *(float4*)&R[r][c0 + i * 4] =
                *(const float4*)&rp[(size_t)(kb * 32 + r) * E_DIM + c0 + i * 4];
        __syncthreads();

        const int w = t >> 6, lane = t & 63;
        const int quad = lane >> 4, col = lane & 15;
#pragma unroll
        for (int h2 = 0; h2 < 2; ++h2) {
            const int nt = w * 2 + h2;
            f16x8 hh, ll;
#pragma unroll
            for (int j = 0; j < 8; ++j) {
                const float v = R[quad * 8 + j][nt * 16 + col] * 64.0f;
                const _Float16 hv = (_Float16)v;
                hh[j] = hv;
                ll[j] = (_Float16)(v - (float)hv);
            }
            const size_t off = ((size_t)((kb * 8 + nt) * 64) + lane) * 8;
            *(f16x8*)&rph[off] = hh;
            *(f16x8*)&rpl[off] = ll;
        }
    }
}

// ---------------------------------------------------------------------------
// Kernel 2: FUSED proj + scores + argmax. Qtile=128, 512 threads, 8 waves,
// grid 256 (1 block/CU).
// Phase 1 (r1-validated): barrier-free direct-from-global proj.
// Phase 2 (r5): SAME wave partition as r4 (wq=w>>1 owns 2 m-tiles, wc=w&1
//   scans a code half; B-frag reused across 2 M) but chunk DOUBLED to 128
//   codes (64 per half, 4 tiles): prefetch distance 1862 -> 3724 cy, which
//   now exceeds worst-case DMA (L3-latency + queueing ~2500-3000 cy), and
//   barrier count halves (128 -> 64). Buffers: 2 x 64 KB, aliasing dead P.
// ---------------------------------------------------------------------------
#define PPITCH   132                  // proj buffer row pitch (dwords)
#define P_BYTES  (128 * PPITCH * 4)   // 67,584 B (phase-1 handoff)
#define CH_BYTES 65536                // 128 codes: 2 halves x 4 tiles x (hi+lo) x 4KB
#define SMEM_BYTES (2 * CH_BYTES)     // 131,072 B (P aliases low 67.5 KB)
#define NCHUNK   64                   // 4096 codes per half / 64

__global__ __launch_bounds__(512, 1) void fused_kernel(
    const float* __restrict__ x,
    const _Float16* __restrict__ rph, const _Float16* __restrict__ rpl,
    const _Float16* __restrict__ ph, const _Float16* __restrict__ pl,
    int* __restrict__ out) {
    __shared__ __align__(16) char SMEM[SMEM_BYTES];   // P (phase1) | Bst[2] (phase2)
    __shared__ float ls[8][32];
    __shared__ int   li[8][32];

    const int tid  = threadIdx.x;
    const int lane = tid & 63;
    const int w    = tid >> 6;
    const int quad = lane >> 4, col = lane & 15;
    const int qb   = blockIdx.x * 128;

    float* Pf  = (float*)SMEM;
    char*  Bst = SMEM;

    // ======================= Phase 1: projection (LDS-free) =================
    const int wn  = w & 3;      // e-tile pair: nt = wn*2 + h
    const int wq1 = w >> 2;     // query 64-half
    const int qbw = qb + wq1 * 64;

    const float* xr[4];
#pragma unroll
    for (int mt = 0; mt < 4; ++mt)
        xr[mt] = x + (size_t)(qbw + mt * 16 + col) * D_IN + quad * 8;

    f32x4 acc[4][2];
#pragma unroll
    for (int mt = 0; mt < 4; ++mt)
#pragma unroll
        for (int h = 0; h < 2; ++h) acc[mt][h] = (f32x4){0.f, 0.f, 0.f, 0.f};

    float4 pA[4][2];
#pragma unroll
    for (int mt = 0; mt < 4; ++mt) {
        pA[mt][0] = *(const float4*)(xr[mt] + 0);
        pA[mt][1] = *(const float4*)(xr[mt] + 4);
    }
    f16x8 bhc[2], blc[2];
#pragma unroll
    for (int h = 0; h < 2; ++h) {
        const size_t off = ((size_t)(wn * 2 + h) * 64 + lane) * 8;
        bhc[h] = *(const f16x8*)&rph[off];
        blc[h] = *(const f16x8*)&rpl[off];
    }

    for (int kb = 0; kb < 32; ++kb) {
        f16x8 ah1[4], al1[4];
#pragma unroll
        for (int mt = 0; mt < 4; ++mt) {
            const float vv[8] = {pA[mt][0].x, pA[mt][0].y, pA[mt][0].z, pA[mt][0].w,
                                 pA[mt][1].x, pA[mt][1].y, pA[mt][1].z, pA[mt][1].w};
            f16x8 hh, ll;
#pragma unroll
            for (int j = 0; j < 8; ++j) {
                const float v = vv[j] * 512.0f;
                const _Float16 hv = (_Float16)v;
                hh[j] = hv;
                ll[j] = (_Float16)(v - (float)hv);
            }
            ah1[mt] = hh;
            al1[mt] = ll;
        }

        if (kb + 1 < 32) {
#pragma unroll
            for (int mt = 0; mt < 4; ++mt) {
                pA[mt][0] = *(const float4*)(xr[mt] + (kb + 1) * 32);
                pA[mt][1] = *(const float4*)(xr[mt] + (kb + 1) * 32 + 4);
            }
        }

        f16x8 bh1[2] = {bhc[0], bhc[1]};
        f16x8 bl1[2] = {blc[0], blc[1]};
        if (kb + 1 < 32) {
#pragma unroll
            for (int h = 0; h < 2; ++h) {
                const size_t off = ((size_t)((kb + 1) * 8 + wn * 2 + h) * 64 + lane) * 8;
                bhc[h] = *(const f16x8*)&rph[off];
                blc[h] = *(const f16x8*)&rpl[off];
            }
        }

#pragma unroll
        for (int mt = 0; mt < 4; ++mt)
#pragma unroll
            for (int h = 0; h < 2; ++h)
                acc[mt][h] = __builtin_amdgcn_mfma_f32_16x16x32_f16(ah1[mt], bh1[h], acc[mt][h], 0, 0, 0);
#pragma unroll
        for (int mt = 0; mt < 4; ++mt)
#pragma unroll
            for (int h = 0; h < 2; ++h)
                acc[mt][h] = __builtin_amdgcn_mfma_f32_16x16x32_f16(ah1[mt], bl1[h], acc[mt][h], 0, 0, 0);
#pragma unroll
        for (int mt = 0; mt < 4; ++mt)
#pragma unroll
            for (int h = 0; h < 2; ++h)
                acc[mt][h] = __builtin_amdgcn_mfma_f32_16x16x32_f16(al1[mt], bh1[h], acc[mt][h], 0, 0, 0);
    }

    // Write proj*16 (f32) to LDS. C/D: row = mt*16 + quad*4 + r, col(e) = h*16 + col.
#pragma unroll
    for (int mt = 0; mt < 4; ++mt)
#pragma unroll
        for (int h = 0; h < 2; ++h)
#pragma unroll
            for (int r = 0; r < 4; ++r) {
                const int row = wq1 * 64 + mt * 16 + quad * 4 + r;
                const int cc  = wn * 32 + h * 16 + col;
                Pf[row * PPITCH + cc] = acc[mt][h][r] * (1.0f / 2048.0f);
            }
    __syncthreads();

    // ======================= Phase 2: scores + argmax =======================
    const int wq = w >> 1;   // query quarter: m-tiles wq*2, wq*2+1
    const int wc = w & 1;    // code half: [wc*4096, wc*4096+4096)

    // A frags from P: A[m=col][k=quad*8+j], split hi/lo, 2 m-tiles.
    f16x8 ah[2][4], al[2][4];
#pragma unroll
    for (int mt2 = 0; mt2 < 2; ++mt2)
#pragma unroll
        for (int kb = 0; kb < 4; ++kb) {
            const int base = ((wq * 2 + mt2) * 16 + col) * PPITCH + kb * 32 + quad * 8;
            const float4 v0 = *(const float4*)&Pf[base];
            const float4 v1 = *(const float4*)&Pf[base + 4];
            const float vv[8] = {v0.x, v0.y, v0.z, v0.w, v1.x, v1.y, v1.z, v1.w};
            f16x8 hh, ll;
#pragma unroll
            for (int j = 0; j < 8; ++j) {
                const _Float16 hv = (_Float16)vv[j];
                hh[j] = hv;
                ll[j] = (_Float16)(vv[j] - (float)hv);
            }
            ah[mt2][kb] = hh;
            al[mt2][kb] = ll;
        }
    __syncthreads();   // everyone done with P; Bst may now overwrite it

    // Staging: 64 x 1KB DMA per chunk, 8 per wave. idx = w*8+i in [0,64):
    //   h2 = idx>>5, tt = (idx>>3)&3, sel = (idx>>2)&1, kb = idx&3.
    // LDS: off = buf*CH_BYTES + idx*1024 (+ lane*16 by HW)
    //     = buf*CH + h2*32768 + tt*8192 + sel*4096 + kb*1024.
    // Global 16-code tile G = h2*256 + c*4 + tt; src = (sel? pl : ph) + (G*4+kb)*1024.
    const char* const sb[2] = {(const char*)ph, (const char*)pl};
    int sh2[8], stt[8], ssel[8], skb[8];
#pragma unroll
    for (int i = 0; i < 8; ++i) {
        const int idx = w * 8 + i;
        sh2[i] = idx >> 5; stt[i] = (idx >> 3) & 3; ssel[i] = (idx >> 2) & 1; skb[i] = idx & 3;
    }

    // prologue: stage chunk 0 into buf 0
#pragma unroll
    for (int i = 0; i < 8; ++i) {
        const int G = sh2[i] * 256 + 0 * 4 + stt[i];
        const char* g = sb[ssel[i]] + (size_t)(G * 4 + skb[i]) * 1024 + (size_t)lane * 16;
        char* l = Bst + (w * 8 + i) * 1024;
        GLL16(g, l);
    }
    __syncthreads();

    float bs[8];
    int   bi[8];
#pragma unroll
    for (int s = 0; s < 8; ++s) { bs[s] = -FLT_MAX; bi[s] = 0; }

    for (int c = 0; c < NCHUNK; ++c) {
        const int cur = c & 1;
        // issue next-chunk DMA early (lands during this chunk's ~3724 cy of MFMA)
        if (c + 1 < NCHUNK) {
            const int nxt = cur ^ 1;
#pragma unroll
            for (int i = 0; i < 8; ++i) {
                const int G = sh2[i] * 256 + (c + 1) * 4 + stt[i];
                const char* g = sb[ssel[i]] + (size_t)(G * 4 + skb[i]) * 1024 + (size_t)lane * 16;
                char* l = Bst + nxt * CH_BYTES + (w * 8 + i) * 1024;
                GLL16(g, l);
            }
        }

        // this wave's half within the chunk: 4 tiles of 16 codes
        const char* bb = Bst + cur * CH_BYTES + wc * 32768 + (size_t)lane * 16;
#pragma unroll
        for (int tt = 0; tt < 4; ++tt) {
            f16x8 bh2[4], bl2[4];
#pragma unroll
            for (int kb = 0; kb < 4; ++kb) {
                bh2[kb] = *(const f16x8*)(bb + tt * 8192 + kb * 1024);
                bl2[kb] = *(const f16x8*)(bb + tt * 8192 + 4096 + kb * 1024);
            }

            f32x4 s0 = (f32x4){0.f, 0.f, 0.f, 0.f};
            f32x4 s1 = (f32x4){0.f, 0.f, 0.f, 0.f};

            __builtin_amdgcn_s_setprio(1);
#pragma unroll
            for (int kb = 0; kb < 4; ++kb) {
                s0 = __builtin_amdgcn_mfma_f32_16x16x32_f16(ah[0][kb], bh2[kb], s0, 0, 0, 0);
                s1 = __builtin_amdgcn_mfma_f32_16x16x32_f16(ah[1][kb], bh2[kb], s1, 0, 0, 0);
            }
#pragma unroll
            for (int kb = 0; kb < 4; ++kb) {
                s0 = __builtin_amdgcn_mfma_f32_16x16x32_f16(ah[0][kb], bl2[kb], s0, 0, 0, 0);
                s1 = __builtin_amdgcn_mfma_f32_16x16x32_f16(ah[1][kb], bl2[kb], s1, 0, 0, 0);
            }
#pragma unroll
            for (int kb = 0; kb < 4; ++kb) {
                s0 = __builtin_amdgcn_mfma_f32_16x16x32_f16(al[0][kb], bh2[kb], s0, 0, 0, 0);
                s1 = __builtin_amdgcn_mfma_f32_16x16x32_f16(al[1][kb], bh2[kb], s1, 0, 0, 0);
            }
            __builtin_amdgcn_s_setprio(0);

            const int code = wc * 4096 + c * 64 + tt * 16 + col;
#pragma unroll
            for (int r = 0; r < 4; ++r) {
                if (s0[r] > bs[r]) { bs[r] = s0[r]; bi[r] = code; }      // ascending: > keeps min idx
            }
#pragma unroll
            for (int r = 0; r < 4; ++r) {
                if (s1[r] > bs[4 + r]) { bs[4 + r] = s1[r]; bi[4 + r] = code; }
            }
        }

        if (c + 1 < NCHUNK) __syncthreads();
    }

    // Reduce the 16 code-columns per query (lanes differ in low 4 bits).
#pragma unroll
    for (int s = 0; s < 8; ++s) {
#pragma unroll
        for (int m = 1; m < 16; m <<= 1) {
            const float os = __shfl_xor(bs[s], m);
            const int   oi = __shfl_xor(bi[s], m);
            if (os > bs[s] || (os == bs[s] && oi < bi[s])) { bs[s] = os; bi[s] = oi; }
        }
    }

    if (col == 0) {
#pragma unroll
        for (int mt2 = 0; mt2 < 2; ++mt2)
#pragma unroll
            for (int r = 0; r < 4; ++r) {
                ls[w][mt2 * 16 + quad * 4 + r] = bs[mt2 * 4 + r];
                li[w][mt2 * 16 + quad * 4 + r] = bi[mt2 * 4 + r];
            }
    }
    __syncthreads();

    // Merge the two code halves (wc=0 codes < wc=1 codes: strict > keeps min idx).
    if (tid < 128) {
        const int q   = tid;
        const int wqf = q >> 5;
        const int q32 = q & 31;
        float s = ls[wqf * 2 + 0][q32];
        int   i = li[wqf * 2 + 0][q32];
        const float os = ls[wqf * 2 + 1][q32];
        if (os > s) { s = os; i = li[wqf * 2 + 1][q32]; }
        out[qb + q] = i;
    }
}

// ---------------------------------------------------------------------------
extern "C" void kernel_launch(void* const* d_in, const int* in_sizes, int n_in,
                              void* d_out, int out_size, void* d_ws, size_t ws_size,
                              hipStream_t stream) {
    const float* x  = (const float*)d_in[0];   // [8,4096,1024]
    const float* rp = (const float*)d_in[1];   // [1024,128]
    const float* cb = (const float*)d_in[2];   // [8192,128]
    int* out = (int*)d_out;                    // [8,4096] int32

    _Float16* ph  = (_Float16*)d_ws;                         // 2 MB
    _Float16* pl  = ph  + (size_t)CB_N * E_DIM;              // 2 MB
    _Float16* rph = pl  + (size_t)CB_N * E_DIM;              // 256 KB
    _Float16* rpl = rph + (size_t)D_IN * E_DIM;              // 256 KB

    pack_all_kernel<<<CB_N / 16 + 32, 256, 0, stream>>>(cb, ph, pl, rp, rph, rpl);
    fused_kernel<<<BN / 128, 512, 0, stream>>>(x, rph, rpl, ph, pl, out);
}